// Round 7
// baseline (158.763 us; speedup 1.0000x reference)
//
#include <hip/hip_runtime.h>
#include <hip/hip_bf16.h>
#include <math.h>

#define D_DIM   4096
#define B_ROWS  4096
#define K_CODES 256
#define MARGIN  3.0      // |approx d2 - exact d2| <= ~1.5 worst-case; 3.0 window
#define BK      256
#define NITER   (D_DIM / BK)   // 16
#define MT      16             // rows per block

// output layout (f32 elements)
#define IDX_OFF   (B_ROWS * D_DIM)                 // 16777216
#define PROBS_OFF (IDX_OFF + B_ROWS)               // 16781312
#define LOSS_OFF  (PROBS_OFF + B_ROWS * K_CODES)   // 17829888

typedef __bf16 bf16x8 __attribute__((ext_vector_type(8)));
typedef float  f32x4  __attribute__((ext_vector_type(4)));

// ws: cbsw[1M] ushort (2 MB) | cc[256] f64
// cbsw layout (16x16x32 B-frag order): element (code k, col c) at ushort
//   (((c>>5)*16 + (k>>4))*64 + ((c>>3)&3)*16 + (k&15))*8 + (c&7)
// so wave reading tile (kt, ct) gets lane-contiguous 16 B runs:
//   lane l -> B[k = kt*32 + (l>>4)*8 + j][code = ct*16 + (l&15)]

static __device__ inline unsigned short f2bf(float f) {
    __hip_bfloat16 h = __float2bfloat16(f);
    return *reinterpret_cast<unsigned short*>(&h);
}

// ---------------------------------------------------------------------------
// prep_cb: one wave per codebook row. Swizzled bf16 codebook (16x16x32 frag
// order) + cc (f64 row sum of squares).
// ---------------------------------------------------------------------------
__global__ __launch_bounds__(64) void prep_cb(const float* __restrict__ cb,
                                              unsigned short* __restrict__ cbsw,
                                              double* __restrict__ cc) {
    const int lane = threadIdx.x & 63;
    const int k = blockIdx.x;                            // code 0..255
    const float4* row4 = (const float4*)(cb + (size_t)k * D_DIM);
    double a0 = 0.0, a1 = 0.0, a2 = 0.0, a3 = 0.0;
#pragma unroll
    for (int i = 0; i < 16; ++i) {
        float4 v = row4[i * 64 + lane];
        a0 += (double)v.x * v.x; a1 += (double)v.y * v.y;
        a2 += (double)v.z * v.z; a3 += (double)v.w * v.w;
        ushort4 h;
        h.x = f2bf(v.x); h.y = f2bf(v.y); h.z = f2bf(v.z); h.w = f2bf(v.w);
        const int c = (i * 64 + lane) * 4;               // col of this chunk
        const size_t idx = (((size_t)(c >> 5) * 16 + (k >> 4)) * 64
                            + ((c >> 3) & 3) * 16 + (k & 15)) * 8 + (c & 7);
        *(ushort4*)&cbsw[idx] = h;
    }
    double s = (a0 + a1) + (a2 + a3);
    for (int off = 32; off; off >>= 1) s += __shfl_xor(s, off);
    if (lane == 0) cc[k] = s;
}

// ---------------------------------------------------------------------------
// vq: fused full-K gemm + argmax + gather. 256 blocks x 512 threads (8 waves).
// Block = 16 rows x 256 codes x K=4096. Wave w owns codes 32w..32w+31
// (two 16-code MFMA tiles), mfma_f32_16x16x32_bf16, B streamed global->VGPR
// (depth-2 pipeline, L2-resident swizzled cbsw), A double-buffered in LDS.
// One barrier per 256-k tile. Dots -> LDS -> per-wave argmax (rows w, w+8)
// with margin + exact f64 refinement, then quant gather. No part buffer.
// ---------------------------------------------------------------------------
__global__ __launch_bounds__(512, 2) void vq(const float* __restrict__ x,
                                             const float* __restrict__ cb,
                                             const unsigned short* __restrict__ cbsw,
                                             const double* __restrict__ cc,
                                             float* __restrict__ out) {
    __shared__ unsigned short As[2][4096];   // [p][kgrp32][row16][8]  2 x 8 KB
    __shared__ float d2s[MT][K_CODES];       // 16 KB dots
    __shared__ float xxs[MT];
    const int t = threadIdx.x;
    const int lane = t & 63, w = t >> 6;     // 8 waves
    const int m0 = blockIdx.x * MT;

    // A staging: thread t -> row t>>5, k-cols (t&31)*4 and +128 of each tile
    const int arow = t >> 5;                 // 0..15
    const int ak = (t & 31) * 4;             // 0..124
    const float* ag = x + (size_t)(m0 + arow) * D_DIM + ak;
    const int aw0 = (ak >> 3) * 128 + arow * 8 + (ak & 7);
    const int aw1 = aw0 + 2048;              // cols +128 -> kgrp+16 -> +16*128
    // B: wave w tiles ct = 2w, 2w+1; per k-step L the fragment is 16 B at
    // (L*8192 + ct*512 + lane*8) ushorts
    const unsigned short* bbase = cbsw + ((size_t)w * 128 + lane) * 8;

    f32x4 acc0 = {0.f, 0.f, 0.f, 0.f}, acc1 = {0.f, 0.f, 0.f, 0.f};
    float sq = 0.f;

    // ---- prologue: A(0)->As[0], A(1)->regs, B k-steps 0,1 -> regs ----
    float4 p0 = *(const float4*)(ag);
    float4 p1 = *(const float4*)(ag + 128);
    float4 c0 = *(const float4*)(ag + BK);
    float4 c1 = *(const float4*)(ag + BK + 128);
    bf16x8 b00 = *(const bf16x8*)(bbase);
    bf16x8 b01 = *(const bf16x8*)(bbase + 512);
    bf16x8 b10 = *(const bf16x8*)(bbase + 8192);
    bf16x8 b11 = *(const bf16x8*)(bbase + 8192 + 512);
    {
        ushort4 h0, h1;
        h0.x = f2bf(p0.x); h0.y = f2bf(p0.y); h0.z = f2bf(p0.z); h0.w = f2bf(p0.w);
        h1.x = f2bf(p1.x); h1.y = f2bf(p1.y); h1.z = f2bf(p1.z); h1.w = f2bf(p1.w);
        *(ushort4*)&As[0][aw0] = h0;
        *(ushort4*)&As[0][aw1] = h1;
        sq += p0.x*p0.x + p0.y*p0.y + p0.z*p0.z + p0.w*p0.w
            + p1.x*p1.x + p1.y*p1.y + p1.z*p1.z + p1.w*p1.w;
    }
    asm volatile("s_waitcnt lgkmcnt(0)" ::: "memory");
    __builtin_amdgcn_s_barrier();
    __builtin_amdgcn_sched_barrier(0);

    // ---- main loop: 16 tiles of 256 k ----
    for (int it = 0; it < NITER; ++it) {
        const int p = it & 1;
        const unsigned short* Ap = &As[p][0];
        unsigned short* An = &As[p ^ 1][0];

        if (it + 1 < NITER) {            // stage A(it+1) into other buffer
            ushort4 h0, h1;
            h0.x = f2bf(c0.x); h0.y = f2bf(c0.y); h0.z = f2bf(c0.z); h0.w = f2bf(c0.w);
            h1.x = f2bf(c1.x); h1.y = f2bf(c1.y); h1.z = f2bf(c1.z); h1.w = f2bf(c1.w);
            *(ushort4*)&An[aw0] = h0;
            *(ushort4*)&An[aw1] = h1;
            sq += c0.x*c0.x + c0.y*c0.y + c0.z*c0.z + c0.w*c0.w
                + c1.x*c1.x + c1.y*c1.y + c1.z*c1.z + c1.w*c1.w;
        }
        const int t2 = (it + 2 < NITER) ? (it + 2) * BK : 0;   // A(it+2) prefetch
        float4 n0 = *(const float4*)(ag + t2);
        float4 n1 = *(const float4*)(ag + t2 + 128);

        __builtin_amdgcn_s_setprio(1);
#pragma unroll
        for (int s = 0; s < 8; ++s) {    // 8 k-steps of 32; B depth-2 pipeline
            bf16x8 af = *(const bf16x8*)&Ap[(s * 64 + lane) * 8];
            if (s & 1) {
                acc0 = __builtin_amdgcn_mfma_f32_16x16x32_bf16(af, b10, acc0, 0, 0, 0);
                acc1 = __builtin_amdgcn_mfma_f32_16x16x32_bf16(af, b11, acc1, 0, 0, 0);
            } else {
                acc0 = __builtin_amdgcn_mfma_f32_16x16x32_bf16(af, b00, acc0, 0, 0, 0);
                acc1 = __builtin_amdgcn_mfma_f32_16x16x32_bf16(af, b01, acc1, 0, 0, 0);
            }
            const int Ln = it * 8 + s + 2;                 // refill used slot
            const size_t bo = (size_t)((Ln < 128) ? Ln : 0) * 8192;
            if (s & 1) { b10 = *(const bf16x8*)(bbase + bo);
                         b11 = *(const bf16x8*)(bbase + bo + 512); }
            else       { b00 = *(const bf16x8*)(bbase + bo);
                         b01 = *(const bf16x8*)(bbase + bo + 512); }
        }
        __builtin_amdgcn_s_setprio(0);

        asm volatile("s_waitcnt lgkmcnt(0)" ::: "memory");   // publish An
        __builtin_amdgcn_s_barrier();
        __builtin_amdgcn_sched_barrier(0);
        c0 = n0; c1 = n1;
    }

    // ---- dots -> LDS; xx reduce (32 lanes share a row) ----
#pragma unroll
    for (int r = 0; r < 4; ++r) {
        const int orow = (lane >> 4) * 4 + r;   // C/D: col=lane&15, row=(lane>>4)*4+r
        d2s[orow][w * 32 + (lane & 15)]      = acc0[r];
        d2s[orow][w * 32 + 16 + (lane & 15)] = acc1[r];
    }
    sq += __shfl_xor(sq, 1); sq += __shfl_xor(sq, 2); sq += __shfl_xor(sq, 4);
    sq += __shfl_xor(sq, 8); sq += __shfl_xor(sq, 16);
    if ((t & 31) == 0) xxs[arow] = sq;
    __syncthreads();

    // ---- per-wave argmax + margin + refine + write (rows w, w+8) ----
#pragma unroll
    for (int rr = 0; rr < 2; ++rr) {
        const int r = w + 8 * rr;
        const int row = m0 + r;
        const double xx = (double)xxs[r];
        const float4 dv = ((const float4*)&d2s[r][0])[lane];
        double v[4];
        v[0] = xx + cc[4 * lane + 0] - 2.0 * (double)dv.x;
        v[1] = xx + cc[4 * lane + 1] - 2.0 * (double)dv.y;
        v[2] = xx + cc[4 * lane + 2] - 2.0 * (double)dv.z;
        v[3] = xx + cc[4 * lane + 3] - 2.0 * (double)dv.w;

        double mx = fmax(fmax(v[0], v[1]), fmax(v[2], v[3]));
        for (int off = 32; off; off >>= 1) mx = fmax(mx, __shfl_xor(mx, off));
        const double thr = mx - MARGIN;

        unsigned long long b[4];
#pragma unroll
        for (int j = 0; j < 4; ++j) b[j] = __ballot(v[j] >= thr);
        const int total = __popcll(b[0]) + __popcll(b[1]) + __popcll(b[2]) + __popcll(b[3]);

        int bestk = 0; double best;
        if (total == 1) {
            best = mx;   // lone candidate IS the max
#pragma unroll
            for (int j = 0; j < 4; ++j)
                if (b[j]) bestk = 4 * (int)__builtin_ctzll(b[j]) + j;
        } else {
            const float4* xrow4 = (const float4*)(x + (size_t)row * D_DIM);
            int flags = 0;
#pragma unroll
            for (int j = 0; j < 4; ++j) if (v[j] >= thr) flags |= 1 << j;
            unsigned long long cand = __ballot(flags != 0);
            best = -1.0e300;
            while (cand) {
                const int lsrc = __builtin_ctzll(cand);
                cand &= cand - 1;
                const int f = __shfl(flags, lsrc);
                for (int j = 0; j < 4; ++j) {
                    if (!((f >> j) & 1)) continue;
                    const int k = 4 * lsrc + j;
                    const float4* crow4 = (const float4*)(cb + (size_t)k * D_DIM);
                    double a0 = 0.0, a1 = 0.0, a2 = 0.0, a3 = 0.0;
#pragma unroll
                    for (int i = 0; i < 16; ++i) {
                        float4 xa = xrow4[i * 64 + lane];
                        float4 ca = crow4[i * 64 + lane];
                        a0 += (double)xa.x * ca.x; a1 += (double)xa.y * ca.y;
                        a2 += (double)xa.z * ca.z; a3 += (double)xa.w * ca.w;
                    }
                    double s = (a0 + a1) + (a2 + a3);
                    for (int off = 32; off; off >>= 1) s += __shfl_xor(s, off);
                    const double d2e = xx + cc[k] - 2.0 * s;
                    if (d2e > best) { best = d2e; bestk = k; }
                }
            }
        }

        if (lane == 0) {
            out[IDX_OFF + row]  = (float)bestk;
            out[LOSS_OFF + row] = (float)(1.25 * best / (double)D_DIM);
        }
        float4 z = make_float4(0.f, 0.f, 0.f, 0.f);
        ((float4*)(out + PROBS_OFF + (size_t)row * K_CODES))[lane] = z;
        const float4* src = (const float4*)(cb + (size_t)bestk * D_DIM);
        float4* dst = (float4*)(out + (size_t)row * D_DIM);
#pragma unroll
        for (int i = 0; i < 16; ++i) dst[i * 64 + lane] = src[i * 64 + lane];
    }
}

// ---------------------------------------------------------------------------
extern "C" void kernel_launch(void* const* d_in, const int* in_sizes, int n_in,
                              void* d_out, int out_size, void* d_ws, size_t ws_size,
                              hipStream_t stream) {
    const float* x  = (const float*)d_in[0];
    const float* cb = (const float*)d_in[1];
    float* out = (float*)d_out;

    unsigned short* cbsw = (unsigned short*)d_ws;
    double*         cc   = (double*)((char*)d_ws + (size_t)K_CODES * D_DIM * sizeof(unsigned short));

    hipLaunchKernelGGL(prep_cb, dim3(256), dim3(64),  0, stream, cb, cbsw, cc);
    hipLaunchKernelGGL(vq,      dim3(256), dim3(512), 0, stream, x, cb, cbsw, cc, out);
}

// Round 8
// 157.388 us; speedup vs baseline: 1.0087x; 1.0087x over previous
//
#include <hip/hip_runtime.h>
#include <hip/hip_bf16.h>
#include <math.h>

#define D_DIM   4096
#define B_ROWS  4096
#define K_CODES 256
#define MARGIN  3.0      // |approx d2 - exact d2| <= ~1.5 worst-case; 3.0 window
#define BK      128
#define NITER   (D_DIM / BK)   // 32
#define MT      16             // rows per block

// output layout (f32 elements)
#define IDX_OFF   (B_ROWS * D_DIM)                 // 16777216
#define PROBS_OFF (IDX_OFF + B_ROWS)               // 16781312
#define LOSS_OFF  (PROBS_OFF + B_ROWS * K_CODES)   // 17829888

typedef __bf16 bf16x8 __attribute__((ext_vector_type(8)));
typedef float  f32x4  __attribute__((ext_vector_type(4)));

// ws: cbsw[1M] ushort (2 MB) | cc[256] f64
// cbsw layout (16x16x32 B-frag order): element (code k, col c) at ushort
//   (((c>>5)*16 + (k>>4))*64 + ((c>>3)&3)*16 + (k&15))*8 + (c&7)
// wave reading k-step L, tile ct: lane l gets 16 B at (L*8192 + ct*512 + l*8):
//   l -> B[k = L*32 + (l>>4)*8 + j][code = ct*16 + (l&15)]

static __device__ inline unsigned short f2bf(float f) {
    __hip_bfloat16 h = __float2bfloat16(f);
    return *reinterpret_cast<unsigned short*>(&h);
}

// ---------------------------------------------------------------------------
// prep_cb: one wave per codebook row. Swizzled bf16 codebook (16x16x32 frag
// order) + cc (f64 row sum of squares).
// ---------------------------------------------------------------------------
__global__ __launch_bounds__(64) void prep_cb(const float* __restrict__ cb,
                                              unsigned short* __restrict__ cbsw,
                                              double* __restrict__ cc) {
    const int lane = threadIdx.x & 63;
    const int k = blockIdx.x;                            // code 0..255
    const float4* row4 = (const float4*)(cb + (size_t)k * D_DIM);
    double a0 = 0.0, a1 = 0.0, a2 = 0.0, a3 = 0.0;
#pragma unroll
    for (int i = 0; i < 16; ++i) {
        float4 v = row4[i * 64 + lane];
        a0 += (double)v.x * v.x; a1 += (double)v.y * v.y;
        a2 += (double)v.z * v.z; a3 += (double)v.w * v.w;
        ushort4 h;
        h.x = f2bf(v.x); h.y = f2bf(v.y); h.z = f2bf(v.z); h.w = f2bf(v.w);
        const int c = (i * 64 + lane) * 4;               // col of this chunk
        const size_t idx = (((size_t)(c >> 5) * 16 + (k >> 4)) * 64
                            + ((c >> 3) & 3) * 16 + (k & 15)) * 8 + (c & 7);
        *(ushort4*)&cbsw[idx] = h;
    }
    double s = (a0 + a1) + (a2 + a3);
    for (int off = 32; off; off >>= 1) s += __shfl_xor(s, off);
    if (lane == 0) cc[k] = s;
}

// B-frag batch load for one 128-k tile (4 k-steps x 2 ct), bank = 8 bf16x8
#define LOAD_BANK(bank, Lbase)                                              \
    _Pragma("unroll")                                                       \
    for (int s = 0; s < 4; ++s) {                                           \
        bank[s][0] = *(const bf16x8*)(bbase + ((size_t)(Lbase) + s) * 8192);        \
        bank[s][1] = *(const bf16x8*)(bbase + ((size_t)(Lbase) + s) * 8192 + 512);  \
    }

#define MFMA_TILE(Ap, bank)                                                 \
    _Pragma("unroll")                                                       \
    for (int s = 0; s < 4; ++s) {                                           \
        bf16x8 af = *(const bf16x8*)&Ap[(s * 64 + lane) * 8];               \
        acc0 = __builtin_amdgcn_mfma_f32_16x16x32_bf16(af, bank[s][0], acc0, 0, 0, 0); \
        acc1 = __builtin_amdgcn_mfma_f32_16x16x32_bf16(af, bank[s][1], acc1, 0, 0, 0); \
    }

#define STAGE_A(buf, v)                                                     \
    {                                                                       \
        ushort4 hh;                                                         \
        hh.x = f2bf((v).x); hh.y = f2bf((v).y);                             \
        hh.z = f2bf((v).z); hh.w = f2bf((v).w);                             \
        *(ushort4*)&buf[aw] = hh;                                           \
        sq += (v).x*(v).x + (v).y*(v).y + (v).z*(v).z + (v).w*(v).w;        \
    }

// ---------------------------------------------------------------------------
// vq: fused full-K gemm + argmax + gather. 256 blocks x 512 threads (8 waves).
// Block = 16 rows x 256 codes x K=4096. Wave w owns codes 32w..32w+31.
// B batch-prefetched a full 128-k tile ahead into a second register bank
// (8 loads in flight across the whole tile -> L2 latency hidden).
// A double-buffered in LDS (1 float4/thread/tile). One barrier per tile.
// ---------------------------------------------------------------------------
__global__ __launch_bounds__(512, 2) void vq(const float* __restrict__ x,
                                             const float* __restrict__ cb,
                                             const unsigned short* __restrict__ cbsw,
                                             const double* __restrict__ cc,
                                             float* __restrict__ out) {
    __shared__ unsigned short As[2][2048];   // [p][kgrp16][row16][8]  2 x 4 KB
    __shared__ float d2s[MT][K_CODES];       // 16 KB dots
    __shared__ float xxs[MT];
    const int t = threadIdx.x;
    const int lane = t & 63, w = t >> 6;     // 8 waves
    const int m0 = blockIdx.x * MT;

    // A staging: thread t -> row t>>5, k-cols (t&31)*4 .. +3 of each 128-tile
    const int arow = t >> 5;                 // 0..15
    const int ak = (t & 31) * 4;             // 0..124
    const float* ag = x + (size_t)(m0 + arow) * D_DIM + ak;
    const int aw = (ak >> 3) * 128 + arow * 8 + (ak & 7);
    const unsigned short* bbase = cbsw + ((size_t)w * 128 + lane) * 8;

    f32x4 acc0 = {0.f, 0.f, 0.f, 0.f}, acc1 = {0.f, 0.f, 0.f, 0.f};
    float sq = 0.f;

    bf16x8 bA[4][2], bB[4][2];

    // ---- prologue: B tile 0 -> bankA, A(0) -> As[0], A(1) -> cA ----
    LOAD_BANK(bA, 0)
    float4 p0 = *(const float4*)(ag);
    float4 cA = *(const float4*)(ag + BK);
    float4 cB;
    STAGE_A(As[0], p0)
    asm volatile("s_waitcnt lgkmcnt(0)" ::: "memory");
    __builtin_amdgcn_s_barrier();
    __builtin_amdgcn_sched_barrier(0);

    // ---- main loop: 16 pairs of 128-k tiles ----
    for (int itp = 0; itp < 16; ++itp) {
        // ---- tile A: it = 2*itp (reads As[0] + bankA) ----
        STAGE_A(As[1], cA)                                     // stage A(it+1)
        {
            const int nt = (2 * itp + 2 < NITER) ? (2 * itp + 2) : 0;
            cB = *(const float4*)(ag + (size_t)nt * BK);       // A(it+2)
        }
        LOAD_BANK(bB, (2 * itp + 1) * 4)                       // B tile it+1
        __builtin_amdgcn_s_setprio(1);
        MFMA_TILE(As[0], bA)
        __builtin_amdgcn_s_setprio(0);
        asm volatile("s_waitcnt lgkmcnt(0)" ::: "memory");
        __builtin_amdgcn_s_barrier();
        __builtin_amdgcn_sched_barrier(0);

        // ---- tile B: it = 2*itp+1 (reads As[1] + bankB) ----
        if (itp < 15) STAGE_A(As[0], cB)                       // stage A(it+1)
        {
            const int nt = (2 * itp + 3 < NITER) ? (2 * itp + 3) : 0;
            cA = *(const float4*)(ag + (size_t)nt * BK);       // A(it+3)
        }
        {
            const int Lb = (2 * itp + 2 < NITER) ? (2 * itp + 2) * 4 : 0;
            LOAD_BANK(bA, Lb)                                  // B tile it+2
        }
        __builtin_amdgcn_s_setprio(1);
        MFMA_TILE(As[1], bB)
        __builtin_amdgcn_s_setprio(0);
        asm volatile("s_waitcnt lgkmcnt(0)" ::: "memory");
        __builtin_amdgcn_s_barrier();
        __builtin_amdgcn_sched_barrier(0);
    }

    // ---- dots -> LDS; xx reduce (32 lanes share a row) ----
#pragma unroll
    for (int r = 0; r < 4; ++r) {
        const int orow = (lane >> 4) * 4 + r;   // C/D: col=lane&15, row=(lane>>4)*4+r
        d2s[orow][w * 32 + (lane & 15)]      = acc0[r];
        d2s[orow][w * 32 + 16 + (lane & 15)] = acc1[r];
    }
    sq += __shfl_xor(sq, 1); sq += __shfl_xor(sq, 2); sq += __shfl_xor(sq, 4);
    sq += __shfl_xor(sq, 8); sq += __shfl_xor(sq, 16);
    if ((t & 31) == 0) xxs[arow] = sq;
    __syncthreads();

    // ---- per-wave argmax + margin + refine + write (rows w, w+8) ----
#pragma unroll
    for (int rr = 0; rr < 2; ++rr) {
        const int r = w + 8 * rr;
        const int row = m0 + r;
        const double xx = (double)xxs[r];
        const float4 dv = ((const float4*)&d2s[r][0])[lane];
        double v[4];
        v[0] = xx + cc[4 * lane + 0] - 2.0 * (double)dv.x;
        v[1] = xx + cc[4 * lane + 1] - 2.0 * (double)dv.y;
        v[2] = xx + cc[4 * lane + 2] - 2.0 * (double)dv.z;
        v[3] = xx + cc[4 * lane + 3] - 2.0 * (double)dv.w;

        double mx = fmax(fmax(v[0], v[1]), fmax(v[2], v[3]));
        for (int off = 32; off; off >>= 1) mx = fmax(mx, __shfl_xor(mx, off));
        const double thr = mx - MARGIN;

        unsigned long long b[4];
#pragma unroll
        for (int j = 0; j < 4; ++j) b[j] = __ballot(v[j] >= thr);
        const int total = __popcll(b[0]) + __popcll(b[1]) + __popcll(b[2]) + __popcll(b[3]);

        int bestk = 0; double best;
        if (total == 1) {
            best = mx;   // lone candidate IS the max
#pragma unroll
            for (int j = 0; j < 4; ++j)
                if (b[j]) bestk = 4 * (int)__builtin_ctzll(b[j]) + j;
        } else {
            const float4* xrow4 = (const float4*)(x + (size_t)row * D_DIM);
            int flags = 0;
#pragma unroll
            for (int j = 0; j < 4; ++j) if (v[j] >= thr) flags |= 1 << j;
            unsigned long long cand = __ballot(flags != 0);
            best = -1.0e300;
            while (cand) {
                const int lsrc = __builtin_ctzll(cand);
                cand &= cand - 1;
                const int f = __shfl(flags, lsrc);
                for (int j = 0; j < 4; ++j) {
                    if (!((f >> j) & 1)) continue;
                    const int k = 4 * lsrc + j;
                    const float4* crow4 = (const float4*)(cb + (size_t)k * D_DIM);
                    double a0 = 0.0, a1 = 0.0, a2 = 0.0, a3 = 0.0;
#pragma unroll
                    for (int i = 0; i < 16; ++i) {
                        float4 xa = xrow4[i * 64 + lane];
                        float4 ca = crow4[i * 64 + lane];
                        a0 += (double)xa.x * ca.x; a1 += (double)xa.y * ca.y;
                        a2 += (double)xa.z * ca.z; a3 += (double)xa.w * ca.w;
                    }
                    double s = (a0 + a1) + (a2 + a3);
                    for (int off = 32; off; off >>= 1) s += __shfl_xor(s, off);
                    const double d2e = xx + cc[k] - 2.0 * s;
                    if (d2e > best) { best = d2e; bestk = k; }
                }
            }
        }

        if (lane == 0) {
            out[IDX_OFF + row]  = (float)bestk;
            out[LOSS_OFF + row] = (float)(1.25 * best / (double)D_DIM);
        }
        float4 z = make_float4(0.f, 0.f, 0.f, 0.f);
        ((float4*)(out + PROBS_OFF + (size_t)row * K_CODES))[lane] = z;
        const float4* src = (const float4*)(cb + (size_t)bestk * D_DIM);
        float4* dst = (float4*)(out + (size_t)row * D_DIM);
#pragma unroll
        for (int i = 0; i < 16; ++i) dst[i * 64 + lane] = src[i * 64 + lane];
    }
}

// ---------------------------------------------------------------------------
extern "C" void kernel_launch(void* const* d_in, const int* in_sizes, int n_in,
                              void* d_out, int out_size, void* d_ws, size_t ws_size,
                              hipStream_t stream) {
    const float* x  = (const float*)d_in[0];
    const float* cb = (const float*)d_in[1];
    float* out = (float*)d_out;

    unsigned short* cbsw = (unsigned short*)d_ws;
    double*         cc   = (double*)((char*)d_ws + (size_t)K_CODES * D_DIM * sizeof(unsigned short));

    hipLaunchKernelGGL(prep_cb, dim3(256), dim3(64),  0, stream, cb, cbsw, cc);
    hipLaunchKernelGGL(vq,      dim3(256), dim3(512), 0, stream, x, cb, cbsw, cc, out);
}